// Round 1
// baseline (1855.726 us; speedup 1.0000x reference)
//
#include <hip/hip_runtime.h>
#include <stdint.h>

#define MROWS 131072                     // 2048 windows * 64 tokens
#define LOG2E 1.44269504088896340736f
#define QSCALE 0.17677669529663688110f   // 32^-0.5

typedef __bf16 bf16x8 __attribute__((ext_vector_type(8)));
typedef float f32x4 __attribute__((ext_vector_type(4)));
typedef int i32x4 __attribute__((ext_vector_type(4)));
typedef unsigned short u16;
typedef u16 u16x4 __attribute__((ext_vector_type(4)));
typedef u16 u16x8 __attribute__((ext_vector_type(8)));

static __device__ __forceinline__ u16 f2bf(float f) {
    uint32_t u = __builtin_bit_cast(uint32_t, f);
    u += 0x7FFFu + ((u >> 16) & 1u);
    return (u16)(u >> 16);
}
static __device__ __forceinline__ float bf2f(u16 h) {
    uint32_t u = ((uint32_t)h) << 16;
    return __builtin_bit_cast(float, u);
}
static __device__ __forceinline__ float shflx(float v, int m) {
    return __shfl_xor(v, m, 64);
}

// ---------------- setup kernels ----------------
__global__ void wt_plain(const float* __restrict__ W, int ldW, int colOff,
                         u16* __restrict__ WT, int K) {
    int idx = blockIdx.x * 256 + threadIdx.x;
    int n = idx / K, k = idx - n * K;
    WT[idx] = f2bf(W[(size_t)k * ldW + colOff + n]);
}
__global__ void wt_split(const float* __restrict__ W, int ldW, int colOff,
                         u16* __restrict__ WTh, u16* __restrict__ WTl, int K) {
    int idx = blockIdx.x * 256 + threadIdx.x;
    int n = idx / K, k = idx - n * K;
    float v = W[(size_t)k * ldW + colOff + n];
    u16 h = f2bf(v);
    WTh[idx] = h;
    WTl[idx] = f2bf(v - bf2f(h));
}
__global__ void bias_pre(const float* __restrict__ table, float* __restrict__ biasM) {
    int h = blockIdx.x;
    for (int e = threadIdx.x; e < 4096; e += 256) {
        int i = e >> 6, j = e & 63;
        int idx = ((i >> 3) - (j >> 3) + 7) * 15 + ((i & 7) - (j & 7) + 7);
        biasM[h * 4096 + e] = table[idx * 16 + h];
    }
}

// ---------------- plain GEMM: out[M,outld] = A(f32)[M,512] @ BT^T + bias, *scale, bf16 out
__global__ __launch_bounds__(256) void gemm_plain(
    const float* __restrict__ A, const u16* __restrict__ BT,
    const float* __restrict__ bias, u16* __restrict__ outp,
    float scale, int outld)
{
    __shared__ u16 As[128 * 64];
    __shared__ u16 Bs[128 * 64];
    const int tid = threadIdx.x;
    const int l = tid & 63, w = tid >> 6;
    const int al = l & 15, g = l >> 4;
    const int wr = w >> 1, wc = w & 1;
    const int m0 = blockIdx.y * 128, n0 = blockIdx.x * 128;
    f32x4 acc[4][4] = {};

    for (int kk = 0; kk < 512; kk += 64) {
        {   // A: fp32 -> bf16 stage
            int r = tid >> 4, c4 = (tid & 15) * 4;
            #pragma unroll
            for (int p = 0; p < 8; ++p) {
                f32x4 v = *(const f32x4*)(A + (size_t)(m0 + p*16 + r) * 512 + kk + c4);
                u16x4 bb;
                bb[0] = f2bf(v[0]); bb[1] = f2bf(v[1]); bb[2] = f2bf(v[2]); bb[3] = f2bf(v[3]);
                *(u16x4*)&As[(p*16 + r) * 64 + c4] = bb;
            }
        }
        {   // B: bf16 stage
            int r = tid >> 3, c8 = (tid & 7) * 8;
            #pragma unroll
            for (int p = 0; p < 4; ++p)
                *(i32x4*)&Bs[(p*32 + r) * 64 + c8] =
                    *(const i32x4*)(BT + (size_t)(n0 + p*32 + r) * 512 + kk + c8);
        }
        __syncthreads();
        #pragma unroll
        for (int kt = 0; kt < 2; ++kt) {
            bf16x8 af[4], bfr[4];
            #pragma unroll
            for (int mt = 0; mt < 4; ++mt)
                af[mt] = *(const bf16x8*)&As[(wr*64 + mt*16 + al) * 64 + kt*32 + g*8];
            #pragma unroll
            for (int nt = 0; nt < 4; ++nt)
                bfr[nt] = *(const bf16x8*)&Bs[(wc*64 + nt*16 + al) * 64 + kt*32 + g*8];
            #pragma unroll
            for (int mt = 0; mt < 4; ++mt)
                #pragma unroll
                for (int nt = 0; nt < 4; ++nt)
                    acc[mt][nt] = __builtin_amdgcn_mfma_f32_16x16x32_bf16(af[mt], bfr[nt], acc[mt][nt], 0, 0, 0);
        }
        __syncthreads();
    }
    #pragma unroll
    for (int nt = 0; nt < 4; ++nt) {
        int col = n0 + wc*64 + nt*16 + al;
        float bv = bias[col];
        #pragma unroll
        for (int mt = 0; mt < 4; ++mt)
            #pragma unroll
            for (int rg = 0; rg < 4; ++rg) {
                size_t row = (size_t)(m0 + wr*64 + mt*16 + g*4 + rg);
                outp[row * outld + col] = f2bf((acc[mt][nt][rg] + bv) * scale);
            }
    }
}

// ---------------- split GEMM (hi/lo bf16 pair, 3-term MFMA)
// FIRST:  A = fp32 (split on the fly), outputs hi/lo bf16 pair (ld 512)
// !FIRST: A = bf16 hi/lo pair (Ap, Ap2), output fp32 (ld 512)
template<bool FIRST>
__global__ __launch_bounds__(256) void gemm_split(
    const void* __restrict__ Ap, const void* __restrict__ Ap2,
    const u16* __restrict__ BTh, const u16* __restrict__ BTl,
    const float* __restrict__ bias,
    void* __restrict__ out1, void* __restrict__ out2)
{
    __shared__ u16 Ah[128*64], Alo[128*64], Bh[128*64], Blo[128*64];
    const int tid = threadIdx.x;
    const int l = tid & 63, w = tid >> 6;
    const int al = l & 15, g = l >> 4;
    const int wr = w >> 1, wc = w & 1;
    const int m0 = blockIdx.y * 128, n0 = blockIdx.x * 128;
    f32x4 acc[4][4] = {};

    for (int kk = 0; kk < 512; kk += 64) {
        if (FIRST) {
            const float* A = (const float*)Ap;
            int r = tid >> 4, c4 = (tid & 15) * 4;
            #pragma unroll
            for (int p = 0; p < 8; ++p) {
                f32x4 v = *(const f32x4*)(A + (size_t)(m0 + p*16 + r) * 512 + kk + c4);
                u16x4 bh_, bl_;
                #pragma unroll
                for (int c = 0; c < 4; ++c) {
                    u16 hh = f2bf(v[c]);
                    bh_[c] = hh;
                    bl_[c] = f2bf(v[c] - bf2f(hh));
                }
                *(u16x4*)&Ah[(p*16 + r) * 64 + c4]  = bh_;
                *(u16x4*)&Alo[(p*16 + r) * 64 + c4] = bl_;
            }
        } else {
            const u16* A1 = (const u16*)Ap;
            const u16* A2 = (const u16*)Ap2;
            int r = tid >> 3, c8 = (tid & 7) * 8;
            #pragma unroll
            for (int p = 0; p < 4; ++p) {
                *(i32x4*)&Ah[(p*32 + r) * 64 + c8]  = *(const i32x4*)(A1 + (size_t)(m0 + p*32 + r) * 512 + kk + c8);
                *(i32x4*)&Alo[(p*32 + r) * 64 + c8] = *(const i32x4*)(A2 + (size_t)(m0 + p*32 + r) * 512 + kk + c8);
            }
        }
        {
            int r = tid >> 3, c8 = (tid & 7) * 8;
            #pragma unroll
            for (int p = 0; p < 4; ++p) {
                *(i32x4*)&Bh[(p*32 + r) * 64 + c8]  = *(const i32x4*)(BTh + (size_t)(n0 + p*32 + r) * 512 + kk + c8);
                *(i32x4*)&Blo[(p*32 + r) * 64 + c8] = *(const i32x4*)(BTl + (size_t)(n0 + p*32 + r) * 512 + kk + c8);
            }
        }
        __syncthreads();
        #pragma unroll
        for (int kt = 0; kt < 2; ++kt) {
            bf16x8 ah[4], alo4[4], bh[4], blo4[4];
            #pragma unroll
            for (int mt = 0; mt < 4; ++mt) {
                ah[mt]   = *(const bf16x8*)&Ah[(wr*64 + mt*16 + al) * 64 + kt*32 + g*8];
                alo4[mt] = *(const bf16x8*)&Alo[(wr*64 + mt*16 + al) * 64 + kt*32 + g*8];
            }
            #pragma unroll
            for (int nt = 0; nt < 4; ++nt) {
                bh[nt]   = *(const bf16x8*)&Bh[(wc*64 + nt*16 + al) * 64 + kt*32 + g*8];
                blo4[nt] = *(const bf16x8*)&Blo[(wc*64 + nt*16 + al) * 64 + kt*32 + g*8];
            }
            #pragma unroll
            for (int mt = 0; mt < 4; ++mt)
                #pragma unroll
                for (int nt = 0; nt < 4; ++nt) {
                    acc[mt][nt] = __builtin_amdgcn_mfma_f32_16x16x32_bf16(ah[mt],   bh[nt],   acc[mt][nt], 0, 0, 0);
                    acc[mt][nt] = __builtin_amdgcn_mfma_f32_16x16x32_bf16(ah[mt],   blo4[nt], acc[mt][nt], 0, 0, 0);
                    acc[mt][nt] = __builtin_amdgcn_mfma_f32_16x16x32_bf16(alo4[mt], bh[nt],   acc[mt][nt], 0, 0, 0);
                }
        }
        __syncthreads();
    }
    #pragma unroll
    for (int nt = 0; nt < 4; ++nt) {
        int col = n0 + wc*64 + nt*16 + al;
        float bv = bias[col];
        #pragma unroll
        for (int mt = 0; mt < 4; ++mt)
            #pragma unroll
            for (int rg = 0; rg < 4; ++rg) {
                size_t row = (size_t)(m0 + wr*64 + mt*16 + g*4 + rg);
                float v = acc[mt][nt][rg] + bv;
                if (FIRST) {
                    u16 hh = f2bf(v);
                    ((u16*)out1)[row * 512 + col] = hh;
                    ((u16*)out2)[row * 512 + col] = f2bf(v - bf2f(hh));
                } else {
                    ((float*)out1)[row * 512 + col] = v;
                }
            }
    }
}

// ---------------- fused window attention ----------------
// 1 block per window, wave w handles heads w, w+4, w+8, w+12.
// S = q k^T (q pre-scaled) + bias + mask; softmax in registers; P split hi/lo
// through per-wave LDS; V gathered from global as hi/lo; O written hi/lo
// aliasing the Q / K buffers (per-head column ownership -> race-free).
__global__ __launch_bounds__(256) void attn64(
    const u16* __restrict__ Q, const u16* __restrict__ Kb,
    const u16* __restrict__ Vh, const u16* __restrict__ Vl,
    const float* __restrict__ biasM, const float* __restrict__ mask,
    u16* __restrict__ Ohi, u16* __restrict__ Olo)
{
    __shared__ u16 Ph[4][64 * 72];
    __shared__ u16 Pl[4][64 * 72];
    const int b = blockIdx.x;
    const int tid = threadIdx.x;
    const int l = tid & 63, w = tid >> 6;
    const int al = l & 15, g = l >> 4;
    const size_t rbase = (size_t)b * 64;
    const float* mk = mask + (size_t)(b & 63) * 4096;

    for (int hq = 0; hq < 4; ++hq) {
        const int h = w + 4 * hq;
        const int co = h * 32;

        bf16x8 qf[4], kf[4];
        #pragma unroll
        for (int t = 0; t < 4; ++t) {
            qf[t] = *(const bf16x8*)(Q  + (rbase + t*16 + al) * 512 + co + g*8);
            kf[t] = *(const bf16x8*)(Kb + (rbase + t*16 + al) * 512 + co + g*8);
        }
        f32x4 s[4][4] = {};
        #pragma unroll
        for (int mt = 0; mt < 4; ++mt)
            #pragma unroll
            for (int nt = 0; nt < 4; ++nt)
                s[mt][nt] = __builtin_amdgcn_mfma_f32_16x16x32_bf16(qf[mt], kf[nt], s[mt][nt], 0, 0, 0);

        const float* bm = biasM + h * 4096;
        #pragma unroll
        for (int mt = 0; mt < 4; ++mt)
            #pragma unroll
            for (int nt = 0; nt < 4; ++nt)
                #pragma unroll
                for (int rg = 0; rg < 4; ++rg) {
                    int i = mt*16 + g*4 + rg, j = nt*16 + al;
                    s[mt][nt][rg] += bm[i*64 + j] + mk[i*64 + j];
                }

        f32x4 sm[4];
        #pragma unroll
        for (int mt = 0; mt < 4; ++mt) {
            f32x4 m4 = s[mt][0];
            #pragma unroll
            for (int nt = 1; nt < 4; ++nt)
                #pragma unroll
                for (int c = 0; c < 4; ++c) m4[c] = fmaxf(m4[c], s[mt][nt][c]);
            #pragma unroll
            for (int d = 1; d < 16; d <<= 1)
                #pragma unroll
                for (int c = 0; c < 4; ++c) m4[c] = fmaxf(m4[c], shflx(m4[c], d));
            #pragma unroll
            for (int nt = 0; nt < 4; ++nt)
                #pragma unroll
                for (int rg = 0; rg < 4; ++rg)
                    s[mt][nt][rg] = exp2f((s[mt][nt][rg] - m4[rg]) * LOG2E);
            f32x4 s4 = s[mt][0];
            #pragma unroll
            for (int nt = 1; nt < 4; ++nt) s4 += s[mt][nt];
            #pragma unroll
            for (int d = 1; d < 16; d <<= 1)
                #pragma unroll
                for (int c = 0; c < 4; ++c) s4[c] += shflx(s4[c], d);
            sm[mt] = s4;
            #pragma unroll
            for (int nt = 0; nt < 4; ++nt)
                #pragma unroll
                for (int rg = 0; rg < 4; ++rg) {
                    float p = s[mt][nt][rg];
                    u16 ph = f2bf(p);
                    int off = (mt*16 + g*4 + rg) * 72 + nt*16 + al;
                    Ph[w][off] = ph;
                    Pl[w][off] = f2bf(p - bf2f(ph));
                }
        }

        // V fragments (hi/lo) gathered from global
        bf16x8 vhf[2][2], vlf[2][2];
        #pragma unroll
        for (int kt = 0; kt < 2; ++kt)
            #pragma unroll
            for (int dt = 0; dt < 2; ++dt) {
                u16x8 th, tl;
                #pragma unroll
                for (int ii = 0; ii < 8; ++ii) {
                    size_t off = (rbase + kt*32 + g*8 + ii) * 512 + co + dt*16 + al;
                    th[ii] = Vh[off];
                    tl[ii] = Vl[off];
                }
                vhf[kt][dt] = __builtin_bit_cast(bf16x8, th);
                vlf[kt][dt] = __builtin_bit_cast(bf16x8, tl);
            }

        f32x4 o[4][2] = {};
        #pragma unroll
        for (int mt = 0; mt < 4; ++mt) {
            bf16x8 pah[2], pal[2];
            #pragma unroll
            for (int kt = 0; kt < 2; ++kt) {
                pah[kt] = *(const bf16x8*)&Ph[w][(mt*16 + al) * 72 + kt*32 + g*8];
                pal[kt] = *(const bf16x8*)&Pl[w][(mt*16 + al) * 72 + kt*32 + g*8];
            }
            #pragma unroll
            for (int dt = 0; dt < 2; ++dt)
                #pragma unroll
                for (int kt = 0; kt < 2; ++kt) {
                    o[mt][dt] = __builtin_amdgcn_mfma_f32_16x16x32_bf16(pah[kt], vhf[kt][dt], o[mt][dt], 0, 0, 0);
                    o[mt][dt] = __builtin_amdgcn_mfma_f32_16x16x32_bf16(pah[kt], vlf[kt][dt], o[mt][dt], 0, 0, 0);
                    o[mt][dt] = __builtin_amdgcn_mfma_f32_16x16x32_bf16(pal[kt], vhf[kt][dt], o[mt][dt], 0, 0, 0);
                }
        }

        #pragma unroll
        for (int mt = 0; mt < 4; ++mt)
            #pragma unroll
            for (int dt = 0; dt < 2; ++dt)
                #pragma unroll
                for (int rg = 0; rg < 4; ++rg) {
                    float v = o[mt][dt][rg] * (1.0f / sm[mt][rg]);
                    size_t off = (rbase + mt*16 + g*4 + rg) * 512 + co + dt*16 + al;
                    u16 hh = f2bf(v);
                    Ohi[off] = hh;
                    Olo[off] = f2bf(v - bf2f(hh));
                }
    }
}

// ---------------- launch ----------------
extern "C" void kernel_launch(void* const* d_in, const int* in_sizes, int n_in,
                              void* d_out, int out_size, void* d_ws, size_t ws_size,
                              hipStream_t stream)
{
    const float* x      = (const float*)d_in[0];
    const float* y      = (const float*)d_in[1];
    const float* mask   = (const float*)d_in[2];
    const float* W_q    = (const float*)d_in[3];
    const float* b_q    = (const float*)d_in[4];
    const float* W_kv   = (const float*)d_in[5];
    const float* b_kv   = (const float*)d_in[6];
    const float* W_proj = (const float*)d_in[7];
    const float* b_proj = (const float*)d_in[8];
    const float* table  = (const float*)d_in[9];

    char* ws = (char*)d_ws;
    const size_t SEG = (size_t)MROWS * 512 * sizeof(u16);   // 128 MB
    u16* Qs     = (u16*)(ws);              // aliased by O_hi after attention
    u16* Ks     = (u16*)(ws + SEG);        // aliased by O_lo after attention
    u16* Vhi    = (u16*)(ws + 2 * SEG);
    u16* Vlo    = (u16*)(ws + 3 * SEG);
    u16* wqT    = (u16*)(ws + 4 * SEG);
    u16* wkvKT  = wqT    + 512 * 512;
    u16* wkvVTh = wkvKT  + 512 * 512;
    u16* wkvVTl = wkvVTh + 512 * 512;
    u16* wprTh  = wkvVTl + 512 * 512;
    u16* wprTl  = wprTh  + 512 * 512;
    float* biasM = (float*)(wprTl + 512 * 512);

    wt_plain<<<1024, 256, 0, stream>>>(W_q, 512, 0, wqT, 512);
    wt_plain<<<1024, 256, 0, stream>>>(W_kv, 1024, 0, wkvKT, 512);
    wt_split<<<1024, 256, 0, stream>>>(W_kv, 1024, 512, wkvVTh, wkvVTl, 512);
    wt_split<<<1024, 256, 0, stream>>>(W_proj, 512, 0, wprTh, wprTl, 512);
    bias_pre<<<16, 256, 0, stream>>>(table, biasM);

    gemm_plain<<<dim3(4, 1024), 256, 0, stream>>>(x, wqT, b_q, Qs, QSCALE, 512);
    gemm_plain<<<dim3(4, 1024), 256, 0, stream>>>(y, wkvKT, b_kv, Ks, 1.0f, 512);
    gemm_split<true><<<dim3(4, 1024), 256, 0, stream>>>(y, nullptr, wkvVTh, wkvVTl, b_kv + 512, Vhi, Vlo);
    attn64<<<2048, 256, 0, stream>>>(Qs, Ks, Vhi, Vlo, biasM, mask, Qs, Ks);
    gemm_split<false><<<dim3(4, 1024), 256, 0, stream>>>(Qs, Ks, wprTh, wprTl, b_proj, d_out, nullptr);
}

// Round 3
// 1531.121 us; speedup vs baseline: 1.2120x; 1.2120x over previous
//
#include <hip/hip_runtime.h>
#include <stdint.h>

#define MROWS 131072                     // 2048 windows * 64 tokens
#define LOG2E 1.44269504088896340736f
#define QSCALE 0.17677669529663688110f   // 32^-0.5

typedef __bf16 bf16x8 __attribute__((ext_vector_type(8)));
typedef float f32x4 __attribute__((ext_vector_type(4)));
typedef int i32x4 __attribute__((ext_vector_type(4)));
typedef unsigned short u16;
typedef u16 u16x4 __attribute__((ext_vector_type(4)));
typedef u16 u16x8 __attribute__((ext_vector_type(8)));

#define GLD16(gp, lp) __builtin_amdgcn_global_load_lds( \
    (const __attribute__((address_space(1))) void*)(gp), \
    (__attribute__((address_space(3))) void*)(lp), 16, 0, 0)

static __device__ __forceinline__ u16 f2bf(float f) {
    uint32_t u = __builtin_bit_cast(uint32_t, f);
    u += 0x7FFFu + ((u >> 16) & 1u);
    return (u16)(u >> 16);
}
static __device__ __forceinline__ float bf2f(u16 h) {
    uint32_t u = ((uint32_t)h) << 16;
    return __builtin_bit_cast(float, u);
}
static __device__ __forceinline__ float shflx(float v, int m) {
    return __shfl_xor(v, m, 64);
}

// ---------------- setup kernels ----------------
__global__ void wt_plain(const float* __restrict__ W, int ldW, int colOff,
                         u16* __restrict__ WT, int K) {
    int idx = blockIdx.x * 256 + threadIdx.x;
    int n = idx / K, k = idx - n * K;
    WT[idx] = f2bf(W[(size_t)k * ldW + colOff + n]);
}
__global__ void wt_split(const float* __restrict__ W, int ldW, int colOff,
                         u16* __restrict__ WTh, u16* __restrict__ WTl, int K) {
    int idx = blockIdx.x * 256 + threadIdx.x;
    int n = idx / K, k = idx - n * K;
    float v = W[(size_t)k * ldW + colOff + n];
    u16 h = f2bf(v);
    WTh[idx] = h;
    WTl[idx] = f2bf(v - bf2f(h));
}
__global__ void bias_pre(const float* __restrict__ table, float* __restrict__ biasM) {
    int h = blockIdx.x;
    for (int e = threadIdx.x; e < 4096; e += 256) {
        int i = e >> 6, j = e & 63;
        int idx = ((i >> 3) - (j >> 3) + 7) * 15 + ((i & 7) - (j & 7) + 7);
        biasM[h * 4096 + e] = table[idx * 16 + h];
    }
}

// ---------------- Q/K GEMM: A fp32 (reg-staged -> bf16), B via global_load_lds
__global__ __launch_bounds__(256) void gemm_qk(
    const float* __restrict__ A, const u16* __restrict__ BT,
    const float* __restrict__ bias, u16* __restrict__ outp, float scale)
{
    __shared__ u16 As[128 * 64];
    __shared__ u16 Bs[128 * 64];
    const int tid = threadIdx.x;
    const int l = tid & 63, w = tid >> 6;
    const int al = l & 15, g = l >> 4;
    const int wr = w >> 1, wc = w & 1;
    const int m0 = blockIdx.y * 128, n0 = blockIdx.x * 128;
    const int srow = tid >> 3, sc8 = (tid & 7) * 8;
    f32x4 acc[4][4] = {};

    for (int kk = 0; kk < 512; kk += 64) {
        #pragma unroll
        for (int r = 0; r < 4; ++r) {
            int row = r * 32 + srow;
            GLD16(BT + (size_t)(n0 + row) * 512 + kk + sc8, &Bs[row * 64 + sc8]);
            const float* ap = A + (size_t)(m0 + row) * 512 + kk + sc8;
            f32x4 v0 = *(const f32x4*)(ap);
            f32x4 v1 = *(const f32x4*)(ap + 4);
            u16x8 hv;
            hv[0]=f2bf(v0[0]); hv[1]=f2bf(v0[1]); hv[2]=f2bf(v0[2]); hv[3]=f2bf(v0[3]);
            hv[4]=f2bf(v1[0]); hv[5]=f2bf(v1[1]); hv[6]=f2bf(v1[2]); hv[7]=f2bf(v1[3]);
            *(u16x8*)&As[row * 64 + sc8] = hv;
        }
        __syncthreads();
        #pragma unroll
        for (int kt = 0; kt < 2; ++kt) {
            bf16x8 af[4], bfr[4];
            #pragma unroll
            for (int mt = 0; mt < 4; ++mt)
                af[mt] = *(const bf16x8*)&As[(wr*64 + mt*16 + al) * 64 + kt*32 + g*8];
            #pragma unroll
            for (int nt = 0; nt < 4; ++nt)
                bfr[nt] = *(const bf16x8*)&Bs[(wc*64 + nt*16 + al) * 64 + kt*32 + g*8];
            #pragma unroll
            for (int mt = 0; mt < 4; ++mt)
                #pragma unroll
                for (int nt = 0; nt < 4; ++nt)
                    acc[mt][nt] = __builtin_amdgcn_mfma_f32_16x16x32_bf16(af[mt], bfr[nt], acc[mt][nt], 0, 0, 0);
        }
        __syncthreads();
    }
    #pragma unroll
    for (int nt = 0; nt < 4; ++nt) {
        int col = n0 + wc*64 + nt*16 + al;
        float bv = bias[col];
        #pragma unroll
        for (int mt = 0; mt < 4; ++mt)
            #pragma unroll
            for (int rg = 0; rg < 4; ++rg) {
                size_t row = (size_t)(m0 + wr*64 + mt*16 + g*4 + rg);
                outp[row * 512 + col] = f2bf((acc[mt][nt][rg] + bv) * scale);
            }
    }
}

// ---------------- V GEMM: A fp32 reg-staged split hi/lo, Bh/Bl via global_load_lds
__global__ __launch_bounds__(256) void gemm_v(
    const float* __restrict__ A,
    const u16* __restrict__ BTh, const u16* __restrict__ BTl,
    const float* __restrict__ bias,
    u16* __restrict__ out1, u16* __restrict__ out2)
{
    __shared__ u16 Ah[128*64], Alo[128*64], Bh[128*64], Blo[128*64];
    const int tid = threadIdx.x;
    const int l = tid & 63, w = tid >> 6;
    const int al = l & 15, g = l >> 4;
    const int wr = w >> 1, wc = w & 1;
    const int m0 = blockIdx.y * 128, n0 = blockIdx.x * 128;
    const int srow = tid >> 3, sc8 = (tid & 7) * 8;
    f32x4 acc[4][4] = {};

    for (int kk = 0; kk < 512; kk += 64) {
        #pragma unroll
        for (int r = 0; r < 4; ++r) {
            int row = r * 32 + srow;
            GLD16(BTh + (size_t)(n0 + row) * 512 + kk + sc8, &Bh[row * 64 + sc8]);
            GLD16(BTl + (size_t)(n0 + row) * 512 + kk + sc8, &Blo[row * 64 + sc8]);
            const float* ap = A + (size_t)(m0 + row) * 512 + kk + sc8;
            f32x4 v0 = *(const f32x4*)(ap);
            f32x4 v1 = *(const f32x4*)(ap + 4);
            u16x8 hv, lv;
            #pragma unroll
            for (int c = 0; c < 4; ++c) {
                u16 hh = f2bf(v0[c]); hv[c] = hh; lv[c] = f2bf(v0[c] - bf2f(hh));
            }
            #pragma unroll
            for (int c = 0; c < 4; ++c) {
                u16 hh = f2bf(v1[c]); hv[4+c] = hh; lv[4+c] = f2bf(v1[c] - bf2f(hh));
            }
            *(u16x8*)&Ah[row * 64 + sc8]  = hv;
            *(u16x8*)&Alo[row * 64 + sc8] = lv;
        }
        __syncthreads();
        #pragma unroll
        for (int kt = 0; kt < 2; ++kt) {
            bf16x8 ah[4], alo4[4], bh[4], blo4[4];
            #pragma unroll
            for (int mt = 0; mt < 4; ++mt) {
                ah[mt]   = *(const bf16x8*)&Ah[(wr*64 + mt*16 + al) * 64 + kt*32 + g*8];
                alo4[mt] = *(const bf16x8*)&Alo[(wr*64 + mt*16 + al) * 64 + kt*32 + g*8];
            }
            #pragma unroll
            for (int nt = 0; nt < 4; ++nt) {
                bh[nt]   = *(const bf16x8*)&Bh[(wc*64 + nt*16 + al) * 64 + kt*32 + g*8];
                blo4[nt] = *(const bf16x8*)&Blo[(wc*64 + nt*16 + al) * 64 + kt*32 + g*8];
            }
            #pragma unroll
            for (int mt = 0; mt < 4; ++mt)
                #pragma unroll
                for (int nt = 0; nt < 4; ++nt) {
                    acc[mt][nt] = __builtin_amdgcn_mfma_f32_16x16x32_bf16(ah[mt],   bh[nt],   acc[mt][nt], 0, 0, 0);
                    acc[mt][nt] = __builtin_amdgcn_mfma_f32_16x16x32_bf16(ah[mt],   blo4[nt], acc[mt][nt], 0, 0, 0);
                    acc[mt][nt] = __builtin_amdgcn_mfma_f32_16x16x32_bf16(alo4[mt], bh[nt],   acc[mt][nt], 0, 0, 0);
                }
        }
        __syncthreads();
    }
    #pragma unroll
    for (int nt = 0; nt < 4; ++nt) {
        int col = n0 + wc*64 + nt*16 + al;
        float bv = bias[col];
        #pragma unroll
        for (int mt = 0; mt < 4; ++mt)
            #pragma unroll
            for (int rg = 0; rg < 4; ++rg) {
                size_t row = (size_t)(m0 + wr*64 + mt*16 + g*4 + rg);
                float v = acc[mt][nt][rg] + bv;
                u16 hh = f2bf(v);
                out1[row * 512 + col] = hh;
                out2[row * 512 + col] = f2bf(v - bf2f(hh));
            }
    }
}

// ---------------- proj GEMM: all four tiles via global_load_lds, fp32 out
__global__ __launch_bounds__(256) void gemm_proj(
    const u16* __restrict__ A1, const u16* __restrict__ A2,
    const u16* __restrict__ BTh, const u16* __restrict__ BTl,
    const float* __restrict__ bias, float* __restrict__ outp)
{
    __shared__ u16 Ah[128*64], Alo[128*64], Bh[128*64], Blo[128*64];
    const int tid = threadIdx.x;
    const int l = tid & 63, w = tid >> 6;
    const int al = l & 15, g = l >> 4;
    const int wr = w >> 1, wc = w & 1;
    const int m0 = blockIdx.y * 128, n0 = blockIdx.x * 128;
    const int srow = tid >> 3, sc8 = (tid & 7) * 8;
    f32x4 acc[4][4] = {};

    for (int kk = 0; kk < 512; kk += 64) {
        #pragma unroll
        for (int r = 0; r < 4; ++r) {
            int row = r * 32 + srow;
            size_t aoff = (size_t)(m0 + row) * 512 + kk + sc8;
            size_t boff = (size_t)(n0 + row) * 512 + kk + sc8;
            int loff = row * 64 + sc8;
            GLD16(A1 + aoff,  &Ah[loff]);
            GLD16(A2 + aoff,  &Alo[loff]);
            GLD16(BTh + boff, &Bh[loff]);
            GLD16(BTl + boff, &Blo[loff]);
        }
        __syncthreads();
        #pragma unroll
        for (int kt = 0; kt < 2; ++kt) {
            bf16x8 ah[4], alo4[4], bh[4], blo4[4];
            #pragma unroll
            for (int mt = 0; mt < 4; ++mt) {
                ah[mt]   = *(const bf16x8*)&Ah[(wr*64 + mt*16 + al) * 64 + kt*32 + g*8];
                alo4[mt] = *(const bf16x8*)&Alo[(wr*64 + mt*16 + al) * 64 + kt*32 + g*8];
            }
            #pragma unroll
            for (int nt = 0; nt < 4; ++nt) {
                bh[nt]   = *(const bf16x8*)&Bh[(wc*64 + nt*16 + al) * 64 + kt*32 + g*8];
                blo4[nt] = *(const bf16x8*)&Blo[(wc*64 + nt*16 + al) * 64 + kt*32 + g*8];
            }
            #pragma unroll
            for (int mt = 0; mt < 4; ++mt)
                #pragma unroll
                for (int nt = 0; nt < 4; ++nt) {
                    acc[mt][nt] = __builtin_amdgcn_mfma_f32_16x16x32_bf16(ah[mt],   bh[nt],   acc[mt][nt], 0, 0, 0);
                    acc[mt][nt] = __builtin_amdgcn_mfma_f32_16x16x32_bf16(ah[mt],   blo4[nt], acc[mt][nt], 0, 0, 0);
                    acc[mt][nt] = __builtin_amdgcn_mfma_f32_16x16x32_bf16(alo4[mt], bh[nt],   acc[mt][nt], 0, 0, 0);
                }
        }
        __syncthreads();
    }
    #pragma unroll
    for (int nt = 0; nt < 4; ++nt) {
        int col = n0 + wc*64 + nt*16 + al;
        float bv = bias[col];
        #pragma unroll
        for (int mt = 0; mt < 4; ++mt)
            #pragma unroll
            for (int rg = 0; rg < 4; ++rg) {
                size_t row = (size_t)(m0 + wr*64 + mt*16 + g*4 + rg);
                outp[row * 512 + col] = acc[mt][nt][rg] + bv;
            }
    }
}

// ---------------- fused window attention ----------------
__global__ __launch_bounds__(256) void attn64(
    const u16* __restrict__ Q, const u16* __restrict__ Kb,
    const u16* __restrict__ Vh, const u16* __restrict__ Vl,
    const float* __restrict__ biasM, const float* __restrict__ mask,
    u16* __restrict__ Ohi, u16* __restrict__ Olo)
{
    __shared__ u16 Ph[4][64 * 72];
    __shared__ u16 Pl[4][64 * 72];
    const int b = blockIdx.x;
    const int tid = threadIdx.x;
    const int l = tid & 63, w = tid >> 6;
    const int al = l & 15, g = l >> 4;
    const size_t rbase = (size_t)b * 64;
    const float* mk = mask + (size_t)(b & 63) * 4096;

    for (int hq = 0; hq < 4; ++hq) {
        const int h = w + 4 * hq;
        const int co = h * 32;

        bf16x8 qf[4], kf[4];
        #pragma unroll
        for (int t = 0; t < 4; ++t) {
            qf[t] = *(const bf16x8*)(Q  + (rbase + t*16 + al) * 512 + co + g*8);
            kf[t] = *(const bf16x8*)(Kb + (rbase + t*16 + al) * 512 + co + g*8);
        }
        f32x4 s[4][4] = {};
        #pragma unroll
        for (int mt = 0; mt < 4; ++mt)
            #pragma unroll
            for (int nt = 0; nt < 4; ++nt)
                s[mt][nt] = __builtin_amdgcn_mfma_f32_16x16x32_bf16(qf[mt], kf[nt], s[mt][nt], 0, 0, 0);

        const float* bm = biasM + h * 4096;
        #pragma unroll
        for (int mt = 0; mt < 4; ++mt)
            #pragma unroll
            for (int nt = 0; nt < 4; ++nt)
                #pragma unroll
                for (int rg = 0; rg < 4; ++rg) {
                    int i = mt*16 + g*4 + rg, j = nt*16 + al;
                    s[mt][nt][rg] += bm[i*64 + j] + mk[i*64 + j];
                }

        f32x4 sm[4];
        #pragma unroll
        for (int mt = 0; mt < 4; ++mt) {
            f32x4 m4 = s[mt][0];
            #pragma unroll
            for (int nt = 1; nt < 4; ++nt)
                #pragma unroll
                for (int c = 0; c < 4; ++c) m4[c] = fmaxf(m4[c], s[mt][nt][c]);
            #pragma unroll
            for (int d = 1; d < 16; d <<= 1)
                #pragma unroll
                for (int c = 0; c < 4; ++c) m4[c] = fmaxf(m4[c], shflx(m4[c], d));
            #pragma unroll
            for (int nt = 0; nt < 4; ++nt)
                #pragma unroll
                for (int rg = 0; rg < 4; ++rg)
                    s[mt][nt][rg] = exp2f((s[mt][nt][rg] - m4[rg]) * LOG2E);
            f32x4 s4 = s[mt][0];
            #pragma unroll
            for (int nt = 1; nt < 4; ++nt) s4 += s[mt][nt];
            #pragma unroll
            for (int d = 1; d < 16; d <<= 1)
                #pragma unroll
                for (int c = 0; c < 4; ++c) s4[c] += shflx(s4[c], d);
            sm[mt] = s4;
            #pragma unroll
            for (int nt = 0; nt < 4; ++nt)
                #pragma unroll
                for (int rg = 0; rg < 4; ++rg) {
                    float p = s[mt][nt][rg];
                    u16 ph = f2bf(p);
                    int off = (mt*16 + g*4 + rg) * 72 + nt*16 + al;
                    Ph[w][off] = ph;
                    Pl[w][off] = f2bf(p - bf2f(ph));
                }
        }

        bf16x8 vhf[2][2], vlf[2][2];
        #pragma unroll
        for (int kt = 0; kt < 2; ++kt)
            #pragma unroll
            for (int dt = 0; dt < 2; ++dt) {
                u16x8 th, tl;
                #pragma unroll
                for (int ii = 0; ii < 8; ++ii) {
                    size_t off = (rbase + kt*32 + g*8 + ii) * 512 + co + dt*16 + al;
                    th[ii] = Vh[off];
                    tl[ii] = Vl[off];
                }
                vhf[kt][dt] = __builtin_bit_cast(bf16x8, th);
                vlf[kt][dt] = __builtin_bit_cast(bf16x8, tl);
            }

        f32x4 o[4][2] = {};
        #pragma unroll
        for (int mt = 0; mt < 4; ++mt) {
            bf16x8 pah[2], pal[2];
            #pragma unroll
            for (int kt = 0; kt < 2; ++kt) {
                pah[kt] = *(const bf16x8*)&Ph[w][(mt*16 + al) * 72 + kt*32 + g*8];
                pal[kt] = *(const bf16x8*)&Pl[w][(mt*16 + al) * 72 + kt*32 + g*8];
            }
            #pragma unroll
            for (int dt = 0; dt < 2; ++dt)
                #pragma unroll
                for (int kt = 0; kt < 2; ++kt) {
                    o[mt][dt] = __builtin_amdgcn_mfma_f32_16x16x32_bf16(pah[kt], vhf[kt][dt], o[mt][dt], 0, 0, 0);
                    o[mt][dt] = __builtin_amdgcn_mfma_f32_16x16x32_bf16(pah[kt], vlf[kt][dt], o[mt][dt], 0, 0, 0);
                    o[mt][dt] = __builtin_amdgcn_mfma_f32_16x16x32_bf16(pal[kt], vhf[kt][dt], o[mt][dt], 0, 0, 0);
                }
        }

        #pragma unroll
        for (int mt = 0; mt < 4; ++mt)
            #pragma unroll
            for (int dt = 0; dt < 2; ++dt)
                #pragma unroll
                for (int rg = 0; rg < 4; ++rg) {
                    float v = o[mt][dt][rg] * (1.0f / sm[mt][rg]);
                    size_t off = (rbase + mt*16 + g*4 + rg) * 512 + co + dt*16 + al;
                    u16 hh = f2bf(v);
                    Ohi[off] = hh;
                    Olo[off] = f2bf(v - bf2f(hh));
                }
    }
}

// ---------------- launch ----------------
extern "C" void kernel_launch(void* const* d_in, const int* in_sizes, int n_in,
                              void* d_out, int out_size, void* d_ws, size_t ws_size,
                              hipStream_t stream)
{
    const float* x      = (const float*)d_in[0];
    const float* y      = (const float*)d_in[1];
    const float* mask   = (const float*)d_in[2];
    const float* W_q    = (const float*)d_in[3];
    const float* b_q    = (const float*)d_in[4];
    const float* W_kv   = (const float*)d_in[5];
    const float* b_kv   = (const float*)d_in[6];
    const float* W_proj = (const float*)d_in[7];
    const float* b_proj = (const float*)d_in[8];
    const float* table  = (const float*)d_in[9];

    char* ws = (char*)d_ws;
    const size_t SEG = (size_t)MROWS * 512 * sizeof(u16);   // 128 MB
    u16* Qs     = (u16*)(ws);              // aliased by O_hi after attention
    u16* Ks     = (u16*)(ws + SEG);        // aliased by O_lo after attention
    u16* Vhi    = (u16*)(ws + 2 * SEG);
    u16* Vlo    = (u16*)(ws + 3 * SEG);
    u16* wqT    = (u16*)(ws + 4 * SEG);
    u16* wkvKT  = wqT    + 512 * 512;
    u16* wkvVTh = wkvKT  + 512 * 512;
    u16* wkvVTl = wkvVTh + 512 * 512;
    u16* wprTh  = wkvVTl + 512 * 512;
    u16* wprTl  = wprTh  + 512 * 512;
    float* biasM = (float*)(wprTl + 512 * 512);

    wt_plain<<<1024, 256, 0, stream>>>(W_q, 512, 0, wqT, 512);
    wt_plain<<<1024, 256, 0, stream>>>(W_kv, 1024, 0, wkvKT, 512);
    wt_split<<<1024, 256, 0, stream>>>(W_kv, 1024, 512, wkvVTh, wkvVTl, 512);
    wt_split<<<1024, 256, 0, stream>>>(W_proj, 512, 0, wprTh, wprTl, 512);
    bias_pre<<<16, 256, 0, stream>>>(table, biasM);

    gemm_qk<<<dim3(4, 1024), 256, 0, stream>>>(x, wqT, b_q, Qs, QSCALE);
    gemm_qk<<<dim3(4, 1024), 256, 0, stream>>>(y, wkvKT, b_kv, Ks, 1.0f);
    gemm_v<<<dim3(4, 1024), 256, 0, stream>>>(y, wkvVTh, wkvVTl, b_kv + 512, Vhi, Vlo);
    attn64<<<2048, 256, 0, stream>>>(Qs, Ks, Vhi, Vlo, biasM, mask, Qs, Ks);
    gemm_proj<<<dim3(4, 1024), 256, 0, stream>>>(Qs, Ks, wprTh, wprTl, b_proj, (float*)d_out);
}

// Round 4
// 1189.489 us; speedup vs baseline: 1.5601x; 1.2872x over previous
//
#include <hip/hip_runtime.h>
#include <stdint.h>

#define MROWS 131072                     // 2048 windows * 64 tokens
#define LOG2E 1.44269504088896340736f
#define QSCALE 0.17677669529663688110f   // 32^-0.5

typedef __bf16 bf16x8 __attribute__((ext_vector_type(8)));
typedef float f32x4 __attribute__((ext_vector_type(4)));
typedef int i32x4 __attribute__((ext_vector_type(4)));
typedef unsigned short u16;
typedef u16 u16x4 __attribute__((ext_vector_type(4)));
typedef u16 u16x8 __attribute__((ext_vector_type(8)));

#define GLD16(gp, lp) __builtin_amdgcn_global_load_lds( \
    (const __attribute__((address_space(1))) void*)(gp), \
    (__attribute__((address_space(3))) void*)(lp), 16, 0, 0)

static __device__ __forceinline__ u16 f2bf(float f) {
    uint32_t u = __builtin_bit_cast(uint32_t, f);
    u += 0x7FFFu + ((u >> 16) & 1u);
    return (u16)(u >> 16);
}
static __device__ __forceinline__ float bf2f(u16 h) {
    uint32_t u = ((uint32_t)h) << 16;
    return __builtin_bit_cast(float, u);
}
static __device__ __forceinline__ float shflx(float v, int m) {
    return __shfl_xor(v, m, 64);
}

// ---------------- setup kernels ----------------
__global__ void wt_plain(const float* __restrict__ W, int ldW, int colOff,
                         u16* __restrict__ WT, int K) {
    int idx = blockIdx.x * 256 + threadIdx.x;
    int n = idx / K, k = idx - n * K;
    WT[idx] = f2bf(W[(size_t)k * ldW + colOff + n]);
}
__global__ void wt_split(const float* __restrict__ W, int ldW, int colOff,
                         u16* __restrict__ WTh, u16* __restrict__ WTl, int K) {
    int idx = blockIdx.x * 256 + threadIdx.x;
    int n = idx / K, k = idx - n * K;
    float v = W[(size_t)k * ldW + colOff + n];
    u16 h = f2bf(v);
    WTh[idx] = h;
    WTl[idx] = f2bf(v - bf2f(h));
}
// combined (rel-pos bias + shift mask), stored TRANSPOSED: cmb[wmod][h][j][i]
__global__ void cmb_pre(const float* __restrict__ table, const float* __restrict__ mask,
                        float* __restrict__ cmb) {
    int wmod = blockIdx.x, h = blockIdx.y;
    float* outp = cmb + (((size_t)wmod * 16 + h) << 12);
    const float* mp = mask + ((size_t)wmod << 12);
    for (int e = threadIdx.x; e < 4096; e += 256) {
        int j = e >> 6, i = e & 63;
        int idx = ((i >> 3) - (j >> 3) + 7) * 15 + ((i & 7) - (j & 7) + 7);
        outp[e] = table[idx * 16 + h] + mp[i * 64 + j];
    }
}

// ---------------- Q/K GEMM: A fp32 (reg-staged -> bf16), B via global_load_lds
__global__ __launch_bounds__(256) void gemm_qk(
    const float* __restrict__ A, const u16* __restrict__ BT,
    const float* __restrict__ bias, u16* __restrict__ outp, float scale)
{
    __shared__ u16 As[128 * 64];
    __shared__ u16 Bs[128 * 64];
    const int tid = threadIdx.x;
    const int l = tid & 63, w = tid >> 6;
    const int al = l & 15, g = l >> 4;
    const int wr = w >> 1, wc = w & 1;
    const int m0 = blockIdx.y * 128, n0 = blockIdx.x * 128;
    const int srow = tid >> 3, sc8 = (tid & 7) * 8;
    f32x4 acc[4][4] = {};

    for (int kk = 0; kk < 512; kk += 64) {
        #pragma unroll
        for (int r = 0; r < 4; ++r) {
            int row = r * 32 + srow;
            GLD16(BT + (size_t)(n0 + row) * 512 + kk + sc8, &Bs[row * 64 + sc8]);
            const float* ap = A + (size_t)(m0 + row) * 512 + kk + sc8;
            f32x4 v0 = *(const f32x4*)(ap);
            f32x4 v1 = *(const f32x4*)(ap + 4);
            u16x8 hv;
            hv[0]=f2bf(v0[0]); hv[1]=f2bf(v0[1]); hv[2]=f2bf(v0[2]); hv[3]=f2bf(v0[3]);
            hv[4]=f2bf(v1[0]); hv[5]=f2bf(v1[1]); hv[6]=f2bf(v1[2]); hv[7]=f2bf(v1[3]);
            *(u16x8*)&As[row * 64 + sc8] = hv;
        }
        __syncthreads();
        #pragma unroll
        for (int kt = 0; kt < 2; ++kt) {
            bf16x8 af[4], bfr[4];
            #pragma unroll
            for (int mt = 0; mt < 4; ++mt)
                af[mt] = *(const bf16x8*)&As[(wr*64 + mt*16 + al) * 64 + kt*32 + g*8];
            #pragma unroll
            for (int nt = 0; nt < 4; ++nt)
                bfr[nt] = *(const bf16x8*)&Bs[(wc*64 + nt*16 + al) * 64 + kt*32 + g*8];
            #pragma unroll
            for (int mt = 0; mt < 4; ++mt)
                #pragma unroll
                for (int nt = 0; nt < 4; ++nt)
                    acc[mt][nt] = __builtin_amdgcn_mfma_f32_16x16x32_bf16(af[mt], bfr[nt], acc[mt][nt], 0, 0, 0);
        }
        __syncthreads();
    }
    #pragma unroll
    for (int nt = 0; nt < 4; ++nt) {
        int col = n0 + wc*64 + nt*16 + al;
        float bv = bias[col];
        #pragma unroll
        for (int mt = 0; mt < 4; ++mt)
            #pragma unroll
            for (int rg = 0; rg < 4; ++rg) {
                size_t row = (size_t)(m0 + wr*64 + mt*16 + g*4 + rg);
                outp[row * 512 + col] = f2bf((acc[mt][nt][rg] + bv) * scale);
            }
    }
}

// ---------------- V GEMM: A fp32 reg-staged split hi/lo, Bh/Bl via global_load_lds
// Output: V^T per head, layout [window][h][d(32)][k(64)], hi/lo
__global__ __launch_bounds__(256) void gemm_v(
    const float* __restrict__ A,
    const u16* __restrict__ BTh, const u16* __restrict__ BTl,
    const float* __restrict__ bias,
    u16* __restrict__ out1, u16* __restrict__ out2)
{
    __shared__ u16 Ah[128*64], Alo[128*64], Bh[128*64], Blo[128*64];
    const int tid = threadIdx.x;
    const int l = tid & 63, w = tid >> 6;
    const int al = l & 15, g = l >> 4;
    const int wr = w >> 1, wc = w & 1;
    const int m0 = blockIdx.y * 128, n0 = blockIdx.x * 128;
    const int srow = tid >> 3, sc8 = (tid & 7) * 8;
    f32x4 acc[4][4] = {};

    for (int kk = 0; kk < 512; kk += 64) {
        #pragma unroll
        for (int r = 0; r < 4; ++r) {
            int row = r * 32 + srow;
            GLD16(BTh + (size_t)(n0 + row) * 512 + kk + sc8, &Bh[row * 64 + sc8]);
            GLD16(BTl + (size_t)(n0 + row) * 512 + kk + sc8, &Blo[row * 64 + sc8]);
            const float* ap = A + (size_t)(m0 + row) * 512 + kk + sc8;
            f32x4 v0 = *(const f32x4*)(ap);
            f32x4 v1 = *(const f32x4*)(ap + 4);
            u16x8 hv, lv;
            #pragma unroll
            for (int c = 0; c < 4; ++c) {
                u16 hh = f2bf(v0[c]); hv[c] = hh; lv[c] = f2bf(v0[c] - bf2f(hh));
            }
            #pragma unroll
            for (int c = 0; c < 4; ++c) {
                u16 hh = f2bf(v1[c]); hv[4+c] = hh; lv[4+c] = f2bf(v1[c] - bf2f(hh));
            }
            *(u16x8*)&Ah[row * 64 + sc8]  = hv;
            *(u16x8*)&Alo[row * 64 + sc8] = lv;
        }
        __syncthreads();
        #pragma unroll
        for (int kt = 0; kt < 2; ++kt) {
            bf16x8 ah[4], alo4[4], bh[4], blo4[4];
            #pragma unroll
            for (int mt = 0; mt < 4; ++mt) {
                ah[mt]   = *(const bf16x8*)&Ah[(wr*64 + mt*16 + al) * 64 + kt*32 + g*8];
                alo4[mt] = *(const bf16x8*)&Alo[(wr*64 + mt*16 + al) * 64 + kt*32 + g*8];
            }
            #pragma unroll
            for (int nt = 0; nt < 4; ++nt) {
                bh[nt]   = *(const bf16x8*)&Bh[(wc*64 + nt*16 + al) * 64 + kt*32 + g*8];
                blo4[nt] = *(const bf16x8*)&Blo[(wc*64 + nt*16 + al) * 64 + kt*32 + g*8];
            }
            #pragma unroll
            for (int mt = 0; mt < 4; ++mt)
                #pragma unroll
                for (int nt = 0; nt < 4; ++nt) {
                    acc[mt][nt] = __builtin_amdgcn_mfma_f32_16x16x32_bf16(ah[mt],   bh[nt],   acc[mt][nt], 0, 0, 0);
                    acc[mt][nt] = __builtin_amdgcn_mfma_f32_16x16x32_bf16(ah[mt],   blo4[nt], acc[mt][nt], 0, 0, 0);
                    acc[mt][nt] = __builtin_amdgcn_mfma_f32_16x16x32_bf16(alo4[mt], bh[nt],   acc[mt][nt], 0, 0, 0);
                }
        }
        __syncthreads();
    }
    #pragma unroll
    for (int nt = 0; nt < 4; ++nt) {
        int col = n0 + wc*64 + nt*16 + al;
        int hh_ = col >> 5, d = col & 31;
        float bv = bias[col];
        #pragma unroll
        for (int mt = 0; mt < 4; ++mt) {
            int row0 = m0 + wr*64 + mt*16 + g*4;
            int window = row0 >> 6, k0 = row0 & 63;
            size_t off = ((size_t)window << 15) + (hh_ << 11) + (d << 6) + k0;
            u16x4 hv, lv;
            #pragma unroll
            for (int rg = 0; rg < 4; ++rg) {
                float v = acc[mt][nt][rg] + bv;
                u16 hb = f2bf(v);
                hv[rg] = hb;
                lv[rg] = f2bf(v - bf2f(hb));
            }
            *(u16x4*)(out1 + off) = hv;
            *(u16x4*)(out2 + off) = lv;
        }
    }
}

// ---------------- proj GEMM: all four tiles via global_load_lds, fp32 out
__global__ __launch_bounds__(256) void gemm_proj(
    const u16* __restrict__ A1, const u16* __restrict__ A2,
    const u16* __restrict__ BTh, const u16* __restrict__ BTl,
    const float* __restrict__ bias, float* __restrict__ outp)
{
    __shared__ u16 Ah[128*64], Alo[128*64], Bh[128*64], Blo[128*64];
    const int tid = threadIdx.x;
    const int l = tid & 63, w = tid >> 6;
    const int al = l & 15, g = l >> 4;
    const int wr = w >> 1, wc = w & 1;
    const int m0 = blockIdx.y * 128, n0 = blockIdx.x * 128;
    const int srow = tid >> 3, sc8 = (tid & 7) * 8;
    f32x4 acc[4][4] = {};

    for (int kk = 0; kk < 512; kk += 64) {
        #pragma unroll
        for (int r = 0; r < 4; ++r) {
            int row = r * 32 + srow;
            size_t aoff = (size_t)(m0 + row) * 512 + kk + sc8;
            size_t boff = (size_t)(n0 + row) * 512 + kk + sc8;
            int loff = row * 64 + sc8;
            GLD16(A1 + aoff,  &Ah[loff]);
            GLD16(A2 + aoff,  &Alo[loff]);
            GLD16(BTh + boff, &Bh[loff]);
            GLD16(BTl + boff, &Blo[loff]);
        }
        __syncthreads();
        #pragma unroll
        for (int kt = 0; kt < 2; ++kt) {
            bf16x8 ah[4], alo4[4], bh[4], blo4[4];
            #pragma unroll
            for (int mt = 0; mt < 4; ++mt) {
                ah[mt]   = *(const bf16x8*)&Ah[(wr*64 + mt*16 + al) * 64 + kt*32 + g*8];
                alo4[mt] = *(const bf16x8*)&Alo[(wr*64 + mt*16 + al) * 64 + kt*32 + g*8];
            }
            #pragma unroll
            for (int nt = 0; nt < 4; ++nt) {
                bh[nt]   = *(const bf16x8*)&Bh[(wc*64 + nt*16 + al) * 64 + kt*32 + g*8];
                blo4[nt] = *(const bf16x8*)&Blo[(wc*64 + nt*16 + al) * 64 + kt*32 + g*8];
            }
            #pragma unroll
            for (int mt = 0; mt < 4; ++mt)
                #pragma unroll
                for (int nt = 0; nt < 4; ++nt) {
                    acc[mt][nt] = __builtin_amdgcn_mfma_f32_16x16x32_bf16(ah[mt],   bh[nt],   acc[mt][nt], 0, 0, 0);
                    acc[mt][nt] = __builtin_amdgcn_mfma_f32_16x16x32_bf16(ah[mt],   blo4[nt], acc[mt][nt], 0, 0, 0);
                    acc[mt][nt] = __builtin_amdgcn_mfma_f32_16x16x32_bf16(alo4[mt], bh[nt],   acc[mt][nt], 0, 0, 0);
                }
        }
        __syncthreads();
    }
    #pragma unroll
    for (int nt = 0; nt < 4; ++nt) {
        int col = n0 + wc*64 + nt*16 + al;
        float bv = bias[col];
        #pragma unroll
        for (int mt = 0; mt < 4; ++mt)
            #pragma unroll
            for (int rg = 0; rg < 4; ++rg) {
                size_t row = (size_t)(m0 + wr*64 + mt*16 + g*4 + rg);
                outp[row * 512 + col] = acc[mt][nt][rg] + bv;
            }
    }
}

// ---------------- fused window attention ----------------
// grid (2048 windows, 4 head-groups); wave w handles head blockIdx.y*4 + w.
// V^T vector loads; combined bias+mask f32x4 loads; P hi/lo via per-wave
// 16-row LDS slice; O written hi/lo aliasing Q/K (per-head columns).
__global__ __launch_bounds__(256) void attn64(
    const u16* __restrict__ Q, const u16* __restrict__ Kb,
    const u16* __restrict__ Vth, const u16* __restrict__ Vtl,
    const float* __restrict__ cmb,
    u16* __restrict__ Ohi, u16* __restrict__ Olo)
{
    __shared__ u16 Ph[4][16 * 72];
    __shared__ u16 Pl[4][16 * 72];
    const int b = blockIdx.x;
    const int tid = threadIdx.x;
    const int l = tid & 63, w = tid >> 6;
    const int al = l & 15, g = l >> 4;
    const size_t rbase = (size_t)b * 64;
    const int h = blockIdx.y * 4 + w;
    const int co = h * 32;

    // V^T fragments: vector loads (issue first — independent of QK/softmax)
    const u16* vth = Vth + ((size_t)b << 15) + (h << 11);
    const u16* vtl = Vtl + ((size_t)b << 15) + (h << 11);
    bf16x8 vhf[2][2], vlf[2][2];
    #pragma unroll
    for (int kt = 0; kt < 2; ++kt)
        #pragma unroll
        for (int dt = 0; dt < 2; ++dt) {
            int voff = ((dt*16 + al) << 6) + kt*32 + g*8;
            vhf[kt][dt] = *(const bf16x8*)(vth + voff);
            vlf[kt][dt] = *(const bf16x8*)(vtl + voff);
        }

    bf16x8 qf[4], kf[4];
    #pragma unroll
    for (int t = 0; t < 4; ++t) {
        qf[t] = *(const bf16x8*)(Q  + (rbase + t*16 + al) * 512 + co + g*8);
        kf[t] = *(const bf16x8*)(Kb + (rbase + t*16 + al) * 512 + co + g*8);
    }
    f32x4 s[4][4] = {};
    #pragma unroll
    for (int mt = 0; mt < 4; ++mt)
        #pragma unroll
        for (int nt = 0; nt < 4; ++nt)
            s[mt][nt] = __builtin_amdgcn_mfma_f32_16x16x32_bf16(qf[mt], kf[nt], s[mt][nt], 0, 0, 0);

    // combined bias+mask (transposed layout [j][i] -> f32x4 over i)
    const float* cp = cmb + ((((size_t)(b & 63)) * 16 + h) << 12);
    #pragma unroll
    for (int mt = 0; mt < 4; ++mt)
        #pragma unroll
        for (int nt = 0; nt < 4; ++nt) {
            f32x4 c4 = *(const f32x4*)(cp + ((nt*16 + al) << 6) + mt*16 + g*4);
            #pragma unroll
            for (int rg = 0; rg < 4; ++rg) s[mt][nt][rg] += c4[rg];
        }

    #pragma unroll
    for (int mt = 0; mt < 4; ++mt) {
        // row max over 64 cols (nt x al-lanes)
        f32x4 m4 = s[mt][0];
        #pragma unroll
        for (int nt = 1; nt < 4; ++nt)
            #pragma unroll
            for (int c = 0; c < 4; ++c) m4[c] = fmaxf(m4[c], s[mt][nt][c]);
        #pragma unroll
        for (int d = 1; d < 16; d <<= 1)
            #pragma unroll
            for (int c = 0; c < 4; ++c) m4[c] = fmaxf(m4[c], shflx(m4[c], d));
        #pragma unroll
        for (int nt = 0; nt < 4; ++nt)
            #pragma unroll
            for (int rg = 0; rg < 4; ++rg)
                s[mt][nt][rg] = exp2f((s[mt][nt][rg] - m4[rg]) * LOG2E);
        f32x4 s4 = s[mt][0];
        #pragma unroll
        for (int nt = 1; nt < 4; ++nt) s4 += s[mt][nt];
        #pragma unroll
        for (int d = 1; d < 16; d <<= 1)
            #pragma unroll
            for (int c = 0; c < 4; ++c) s4[c] += shflx(s4[c], d);
        // write P slice (rows mt*16..mt*16+15) hi/lo
        #pragma unroll
        for (int nt = 0; nt < 4; ++nt)
            #pragma unroll
            for (int rg = 0; rg < 4; ++rg) {
                float p = s[mt][nt][rg];
                u16 ph = f2bf(p);
                int off = (g*4 + rg) * 72 + nt*16 + al;
                Ph[w][off] = ph;
                Pl[w][off] = f2bf(p - bf2f(ph));
            }
        // PV for this 16-row slice
        bf16x8 pah[2], pal[2];
        #pragma unroll
        for (int kt = 0; kt < 2; ++kt) {
            pah[kt] = *(const bf16x8*)&Ph[w][al * 72 + kt*32 + g*8];
            pal[kt] = *(const bf16x8*)&Pl[w][al * 72 + kt*32 + g*8];
        }
        f32x4 o[2] = {};
        #pragma unroll
        for (int dt = 0; dt < 2; ++dt)
            #pragma unroll
            for (int kt = 0; kt < 2; ++kt) {
                o[dt] = __builtin_amdgcn_mfma_f32_16x16x32_bf16(pah[kt], vhf[kt][dt], o[dt], 0, 0, 0);
                o[dt] = __builtin_amdgcn_mfma_f32_16x16x32_bf16(pah[kt], vlf[kt][dt], o[dt], 0, 0, 0);
                o[dt] = __builtin_amdgcn_mfma_f32_16x16x32_bf16(pal[kt], vhf[kt][dt], o[dt], 0, 0, 0);
            }
        #pragma unroll
        for (int dt = 0; dt < 2; ++dt)
            #pragma unroll
            for (int rg = 0; rg < 4; ++rg) {
                float v = o[dt][rg] * (1.0f / s4[rg]);
                size_t off = (rbase + mt*16 + g*4 + rg) * 512 + co + dt*16 + al;
                u16 hh = f2bf(v);
                Ohi[off] = hh;
                Olo[off] = f2bf(v - bf2f(hh));
            }
    }
}

// ---------------- launch ----------------
extern "C" void kernel_launch(void* const* d_in, const int* in_sizes, int n_in,
                              void* d_out, int out_size, void* d_ws, size_t ws_size,
                              hipStream_t stream)
{
    const float* x      = (const float*)d_in[0];
    const float* y      = (const float*)d_in[1];
    const float* mask   = (const float*)d_in[2];
    const float* W_q    = (const float*)d_in[3];
    const float* b_q    = (const float*)d_in[4];
    const float* W_kv   = (const float*)d_in[5];
    const float* b_kv   = (const float*)d_in[6];
    const float* W_proj = (const float*)d_in[7];
    const float* b_proj = (const float*)d_in[8];
    const float* table  = (const float*)d_in[9];

    char* ws = (char*)d_ws;
    const size_t SEG = (size_t)MROWS * 512 * sizeof(u16);   // 128 MB
    u16* Qs     = (u16*)(ws);              // aliased by O_hi after attention
    u16* Ks     = (u16*)(ws + SEG);        // aliased by O_lo after attention
    u16* Vth    = (u16*)(ws + 2 * SEG);    // V^T hi [win][h][d][k]
    u16* Vtl    = (u16*)(ws + 3 * SEG);    // V^T lo
    u16* wqT    = (u16*)(ws + 4 * SEG);
    u16* wkvKT  = wqT    + 512 * 512;
    u16* wkvVTh = wkvKT  + 512 * 512;
    u16* wkvVTl = wkvVTh + 512 * 512;
    u16* wprTh  = wkvVTl + 512 * 512;
    u16* wprTl  = wprTh  + 512 * 512;
    float* cmb  = (float*)(wprTl + 512 * 512);   // 64*16*4096*4B = 16 MB

    wt_plain<<<1024, 256, 0, stream>>>(W_q, 512, 0, wqT, 512);
    wt_plain<<<1024, 256, 0, stream>>>(W_kv, 1024, 0, wkvKT, 512);
    wt_split<<<1024, 256, 0, stream>>>(W_kv, 1024, 512, wkvVTh, wkvVTl, 512);
    wt_split<<<1024, 256, 0, stream>>>(W_proj, 512, 0, wprTh, wprTl, 512);
    cmb_pre<<<dim3(64, 16), 256, 0, stream>>>(table, mask, cmb);

    gemm_qk<<<dim3(4, 1024), 256, 0, stream>>>(x, wqT, b_q, Qs, QSCALE);
    gemm_qk<<<dim3(4, 1024), 256, 0, stream>>>(y, wkvKT, b_kv, Ks, 1.0f);
    gemm_v<<<dim3(4, 1024), 256, 0, stream>>>(y, wkvVTh, wkvVTl, b_kv + 512, Vth, Vtl);
    attn64<<<dim3(2048, 4), 256, 0, stream>>>(Qs, Ks, Vth, Vtl, cmb, Qs, Ks);
    gemm_proj<<<dim3(4, 1024), 256, 0, stream>>>(Qs, Ks, wprTh, wprTl, b_proj, (float*)d_out);
}